// Round 10
// baseline (1345.855 us; speedup 1.0000x reference)
//
#include <hip/hip_runtime.h>
#include <math.h>

#define N_NODES 100000
#define N_EDGES 1600000
#define LN_EPS 1e-5f

// bucketed aggregation: 16 nodes per bucket, FIXED-capacity segments
#define B_SHIFT 4
#define B_NODES 16
#define N_BUCKETS 6250           // 100000 / 16
#define SEG_CAP 448              // fixed slots/bucket (mean 256, max~330 @12 sigma)

typedef __attribute__((ext_vector_type(8))) short short8;
typedef __attribute__((ext_vector_type(4))) float f32x4;
#define MFMA16(a, b, c) __builtin_amdgcn_mfma_f32_16x16x32_bf16(a, b, c, 0, 0, 0)

#define LOG2E 1.442695040888963f

#if __has_builtin(__builtin_amdgcn_exp2f) && __has_builtin(__builtin_amdgcn_rcpf)
__device__ __forceinline__ float sigmoidf_(float v) {
    return __builtin_amdgcn_rcpf(1.0f + __builtin_amdgcn_exp2f(-LOG2E * v));
}
#else
__device__ __forceinline__ float sigmoidf_(float v) { return 1.0f / (1.0f + __expf(-v)); }
#endif
__device__ __forceinline__ float siluf_(float v) { return v * sigmoidf_(v); }

// bf16 pack (round-to-nearest-even)
__device__ __forceinline__ unsigned short f2bf_(float f) {
    unsigned int u = __float_as_uint(f);
    unsigned int rounded = u + 0x7FFF + ((u >> 16) & 1);
    return (unsigned short)(rounded >> 16);
}

// ---------------------------------------------------------------------------
// KW: convert + transpose weights to bf16 [n][k]; ALSO inits bucket cursors
// (folded p3i: one fewer dispatch).
// ---------------------------------------------------------------------------
__global__ __launch_bounds__(256) void kw(const float* __restrict__ W1,
                                          const float* __restrict__ W2,
                                          const float* __restrict__ resW,
                                          const float* __restrict__ aggW,
                                          unsigned short* __restrict__ w1t,
                                          unsigned short* __restrict__ w2t,
                                          unsigned short* __restrict__ rest,
                                          unsigned short* __restrict__ aggt,
                                          int* __restrict__ bcursor) {
    const int idx = blockIdx.x * 256 + threadIdx.x;  // 0..88575
    if (idx < 32768) {
        const int n = idx >> 8, k = idx & 255;
        w1t[idx] = f2bf_(W1[k * 128 + n]);
    } else if (idx < 49152) {
        const int i = idx - 32768, n = i >> 7, k = i & 127;
        w2t[i] = f2bf_(W2[k * 128 + n]);
    } else if (idx < 65536) {
        const int i = idx - 49152, n = i >> 7, k = i & 127;
        rest[i] = f2bf_(resW[k * 128 + n]);
    } else if (idx < 81920) {
        const int i = idx - 65536, n = i >> 7, k = i & 127;
        aggt[i] = f2bf_(aggW[k * 128 + n]);
    } else if (idx < 81920 + N_BUCKETS) {
        const int n = idx - 81920;
        bcursor[n] = n * SEG_CAP;
    }
}

// ---------------------------------------------------------------------------
// K1 (MFMA): y16 = bf16( silu(x @ aggW + b) ).  32 nodes/block, 256 thr.
// ---------------------------------------------------------------------------
__global__ __launch_bounds__(256) void k1_y(const float* __restrict__ x,
                                            const unsigned short* __restrict__ aggt,
                                            const float* __restrict__ b,
                                            unsigned short* __restrict__ y16) {
    __shared__ unsigned short A1[32 * 136];
    __shared__ unsigned short O[32 * 136];
    const int t = threadIdx.x;
    const int n0 = blockIdx.x * 32;
    const float4* x4 = (const float4*)x;

#pragma unroll
    for (int r = 0; r < 4; ++r) {
        const int idx = t + r * 256;          // 32 nodes x 32 float4
        const int node = idx >> 5, c4 = idx & 31;
        const float4 v = x4[(n0 + node) * 32 + c4];
        ushort4 p;
        p.x = f2bf_(v.x); p.y = f2bf_(v.y); p.z = f2bf_(v.z); p.w = f2bf_(v.w);
        *(ushort4*)&A1[node * 136 + c4 * 4] = p;
    }
    __syncthreads();

    const int w = t >> 6, lane = t & 63, nq = lane & 15, quad = lane >> 4;
    f32x4 c[2][2] = {};
#pragma unroll
    for (int ks = 0; ks < 4; ++ks) {
        const int k0 = ks * 32 + quad * 8;
        const short8 a0 = *(const short8*)&A1[(nq)*136 + k0];
        const short8 a1 = *(const short8*)&A1[(16 + nq) * 136 + k0];
        const short8 b0 = *(const short8*)&aggt[(w * 32 + nq) * 128 + k0];
        const short8 b1 = *(const short8*)&aggt[(w * 32 + 16 + nq) * 128 + k0];
        c[0][0] = MFMA16(a0, b0, c[0][0]);
        c[0][1] = MFMA16(a0, b1, c[0][1]);
        c[1][0] = MFMA16(a1, b0, c[1][0]);
        c[1][1] = MFMA16(a1, b1, c[1][1]);
    }
    const float bc0 = b[w * 32 + nq], bc1 = b[w * 32 + 16 + nq];
#pragma unroll
    for (int mt = 0; mt < 2; ++mt)
#pragma unroll
        for (int r = 0; r < 4; ++r) {
            const int row = mt * 16 + quad * 4 + r;
            O[row * 136 + w * 32 + nq] = f2bf_(siluf_(c[mt][0][r] + bc0));
            O[row * 136 + w * 32 + 16 + nq] = f2bf_(siluf_(c[mt][1][r] + bc1));
        }
    __syncthreads();

#pragma unroll
    for (int r = 0; r < 2; ++r) {
        const int idx = t + r * 256;          // 32 rows x 16 chunks(16B)
        const int row = idx >> 4, c8 = idx & 15;
        const short8 v = *(const short8*)&O[row * 136 + c8 * 8];
        *(short8*)&y16[(n0 + row) * 128 + c8 * 8] = v;
    }
}

// ---------------------------------------------------------------------------
// P3G (fused gate + scatter), 2 edges/thread, 128-thread blocks, 6250 blocks.
// Plateaued at ~101us across 6 configs (r4-r9); left at the verified-best.
// ---------------------------------------------------------------------------
__global__ __launch_bounds__(128) void p3g(const float* __restrict__ attr,
                                           const float* __restrict__ W1,
                                           const float* __restrict__ b1,
                                           const float* __restrict__ W2,
                                           const float* __restrict__ b2,
                                           const int* __restrict__ src,
                                           const int* __restrict__ dst,
                                           int* __restrict__ bcursor,
                                           uint2* __restrict__ brec) {
    __shared__ float4 W1s[128];
    __shared__ float4 W2s[32];
    __shared__ float4 b1s[32];
    const int t = threadIdx.x;
    W1s[t] = ((const float4*)W1)[t];          // 128 threads cover W1 exactly
    if (t < 32) {
        W2s[t] = ((const float4*)W2)[t];
        b1s[t] = ((const float4*)b1)[t];
    }
    __syncthreads();

    const int e0 = blockIdx.x * 256 + t;      // 6250 blocks x 256 edges
    const int e1 = e0 + 128;
    const float4 a0 = ((const float4*)attr)[e0];
    const float4 a1 = ((const float4*)attr)[e1];
    const int s0 = src[e0], s1 = src[e1];
    const int d0 = dst[e0], d1 = dst[e1];
    float acc0 = 0.f, acc1 = 0.f;
#pragma unroll 8
    for (int j4 = 0; j4 < 32; ++j4) {
        const float4 r0 = W1s[j4];
        const float4 r1 = W1s[32 + j4];
        const float4 r2 = W1s[64 + j4];
        const float4 r3 = W1s[96 + j4];
        const float4 bb = b1s[j4];
        const float4 w2v = W2s[j4];
        // edge 0
        float hx = fmaf(a0.x, r0.x, fmaf(a0.y, r1.x, fmaf(a0.z, r2.x, fmaf(a0.w, r3.x, bb.x))));
        float hy = fmaf(a0.x, r0.y, fmaf(a0.y, r1.y, fmaf(a0.z, r2.y, fmaf(a0.w, r3.y, bb.y))));
        float hz = fmaf(a0.x, r0.z, fmaf(a0.y, r1.z, fmaf(a0.z, r2.z, fmaf(a0.w, r3.z, bb.z))));
        float hw = fmaf(a0.x, r0.w, fmaf(a0.y, r1.w, fmaf(a0.z, r2.w, fmaf(a0.w, r3.w, bb.w))));
        // edge 1 (independent chain — fills trans/fma latency of edge 0)
        float gx = fmaf(a1.x, r0.x, fmaf(a1.y, r1.x, fmaf(a1.z, r2.x, fmaf(a1.w, r3.x, bb.x))));
        float gy = fmaf(a1.x, r0.y, fmaf(a1.y, r1.y, fmaf(a1.z, r2.y, fmaf(a1.w, r3.y, bb.y))));
        float gz = fmaf(a1.x, r0.z, fmaf(a1.y, r1.z, fmaf(a1.z, r2.z, fmaf(a1.w, r3.z, bb.z))));
        float gw = fmaf(a1.x, r0.w, fmaf(a1.y, r1.w, fmaf(a1.z, r2.w, fmaf(a1.w, r3.w, bb.w))));
        acc0 = fmaf(siluf_(hx), w2v.x, acc0);
        acc1 = fmaf(siluf_(gx), w2v.x, acc1);
        acc0 = fmaf(siluf_(hy), w2v.y, acc0);
        acc1 = fmaf(siluf_(gy), w2v.y, acc1);
        acc0 = fmaf(siluf_(hz), w2v.z, acc0);
        acc1 = fmaf(siluf_(gz), w2v.z, acc1);
        acc0 = fmaf(siluf_(hw), w2v.w, acc0);
        acc1 = fmaf(siluf_(gw), w2v.w, acc1);
    }
    const float b2c = b2[0];
    const float ew0 = sigmoidf_(acc0 + b2c);
    const float ew1 = sigmoidf_(acc1 + b2c);
    const int bk0 = d0 >> B_SHIFT;
    const int slot0 = atomicAdd(&bcursor[bk0], 1);
    if (slot0 < (bk0 + 1) * SEG_CAP)   // capacity guard (unreachable for this input)
        brec[slot0] = make_uint2((unsigned)s0 | ((unsigned)(d0 & (B_NODES - 1)) << 27),
                                 __float_as_uint(ew0));
    const int bk1 = d1 >> B_SHIFT;
    const int slot1 = atomicAdd(&bcursor[bk1], 1);
    if (slot1 < (bk1 + 1) * SEG_CAP)
        brec[slot1] = make_uint2((unsigned)s1 | ((unsigned)(d1 & (B_NODES - 1)) << 27),
                                 __float_as_uint(ew1));
}

// ---------------------------------------------------------------------------
// PB (sort-free streaming gather): one block per bucket. Waves split the
// record range evenly; each record: y-row gather -> LDS f32 atomicAdd into
// per-node accumulators. No counting sort, no per-node pipeline drain, no
// wave load-imbalance. accx/accy rows are 2 lanes/bank (conflict-free, m136).
// ---------------------------------------------------------------------------
__global__ __launch_bounds__(256) void pB(const unsigned short* __restrict__ y16,
                                          const int* __restrict__ bcursor,
                                          const uint2* __restrict__ brec,
                                          float* __restrict__ agg) {
    __shared__ float accx[B_NODES][64];   // 4 KB (dim = 2*lane)
    __shared__ float accy[B_NODES][64];   // 4 KB (dim = 2*lane+1)
    __shared__ int hist[B_NODES];

    const int t = threadIdx.x;
    const int b = blockIdx.x;
    const int base = b * SEG_CAP;
    int c = bcursor[b] - base;
    if (c > SEG_CAP) c = SEG_CAP;  // guards segment bound (unreachable)

    if (t < B_NODES) hist[t] = 0;
    for (int i = t; i < B_NODES * 64; i += 256) {
        ((float*)accx)[i] = 0.f;
        ((float*)accy)[i] = 0.f;
    }
    __syncthreads();

    // per-node counts (coalesced brec read, 1 LDS atomic per record)
    for (int i = t; i < c; i += 256) {
        atomicAdd(&hist[brec[base + i].x >> 27], 1);
    }

    // gather-accumulate: wave w owns records [w*cq, min((w+1)*cq, c))
    const int w = t >> 6, lane = t & 63;
    const unsigned int* y32 = (const unsigned int*)y16;
    const int cq = (c + 3) >> 2;
    int p = w * cq;
    int pend = (w + 1) * cq;
    if (pend > c) pend = c;
    for (; p + 8 <= pend; p += 8) {
        const uint2 r0 = brec[base + p];
        const uint2 r1 = brec[base + p + 1];
        const uint2 r2 = brec[base + p + 2];
        const uint2 r3 = brec[base + p + 3];
        const uint2 r4 = brec[base + p + 4];
        const uint2 r5 = brec[base + p + 5];
        const uint2 r6 = brec[base + p + 6];
        const uint2 r7 = brec[base + p + 7];
        const unsigned int u0 = y32[(r0.x & 0x7FFFFFFu) * 64 + lane];
        const unsigned int u1 = y32[(r1.x & 0x7FFFFFFu) * 64 + lane];
        const unsigned int u2 = y32[(r2.x & 0x7FFFFFFu) * 64 + lane];
        const unsigned int u3 = y32[(r3.x & 0x7FFFFFFu) * 64 + lane];
        const unsigned int u4 = y32[(r4.x & 0x7FFFFFFu) * 64 + lane];
        const unsigned int u5 = y32[(r5.x & 0x7FFFFFFu) * 64 + lane];
        const unsigned int u6 = y32[(r6.x & 0x7FFFFFFu) * 64 + lane];
        const unsigned int u7 = y32[(r7.x & 0x7FFFFFFu) * 64 + lane];
        const float w0 = __uint_as_float(r0.y);
        const float w1 = __uint_as_float(r1.y);
        const float w2 = __uint_as_float(r2.y);
        const float w3 = __uint_as_float(r3.y);
        const float w4 = __uint_as_float(r4.y);
        const float w5 = __uint_as_float(r5.y);
        const float w6 = __uint_as_float(r6.y);
        const float w7 = __uint_as_float(r7.y);
        atomicAdd(&accx[r0.x >> 27][lane], __uint_as_float(u0 << 16) * w0);
        atomicAdd(&accy[r0.x >> 27][lane], __uint_as_float(u0 & 0xFFFF0000u) * w0);
        atomicAdd(&accx[r1.x >> 27][lane], __uint_as_float(u1 << 16) * w1);
        atomicAdd(&accy[r1.x >> 27][lane], __uint_as_float(u1 & 0xFFFF0000u) * w1);
        atomicAdd(&accx[r2.x >> 27][lane], __uint_as_float(u2 << 16) * w2);
        atomicAdd(&accy[r2.x >> 27][lane], __uint_as_float(u2 & 0xFFFF0000u) * w2);
        atomicAdd(&accx[r3.x >> 27][lane], __uint_as_float(u3 << 16) * w3);
        atomicAdd(&accy[r3.x >> 27][lane], __uint_as_float(u3 & 0xFFFF0000u) * w3);
        atomicAdd(&accx[r4.x >> 27][lane], __uint_as_float(u4 << 16) * w4);
        atomicAdd(&accy[r4.x >> 27][lane], __uint_as_float(u4 & 0xFFFF0000u) * w4);
        atomicAdd(&accx[r5.x >> 27][lane], __uint_as_float(u5 << 16) * w5);
        atomicAdd(&accy[r5.x >> 27][lane], __uint_as_float(u5 & 0xFFFF0000u) * w5);
        atomicAdd(&accx[r6.x >> 27][lane], __uint_as_float(u6 << 16) * w6);
        atomicAdd(&accy[r6.x >> 27][lane], __uint_as_float(u6 & 0xFFFF0000u) * w6);
        atomicAdd(&accx[r7.x >> 27][lane], __uint_as_float(u7 << 16) * w7);
        atomicAdd(&accy[r7.x >> 27][lane], __uint_as_float(u7 & 0xFFFF0000u) * w7);
    }
    for (; p < pend; ++p) {
        const uint2 r0 = brec[base + p];
        const unsigned int u0 = y32[(r0.x & 0x7FFFFFFu) * 64 + lane];
        const float w0 = __uint_as_float(r0.y);
        atomicAdd(&accx[r0.x >> 27][lane], __uint_as_float(u0 << 16) * w0);
        atomicAdd(&accy[r0.x >> 27][lane], __uint_as_float(u0 & 0xFFFF0000u) * w0);
    }
    __syncthreads();

    // epilogue: mean + coalesced store (agg aliased onto d_out)
    for (int i = t; i < B_NODES * 64; i += 256) {
        const int node = i >> 6, l2 = i & 63;
        const float inv = 1.0f / fmaxf((float)hist[node], 1.0f);
        ((float2*)agg)[(b * B_NODES + node) * 64 + l2] =
            make_float2(accx[node][l2] * inv, accy[node][l2] * inv);
    }
}

// ---------------------------------------------------------------------------
// K4 (MFMA): fused update MLP + residual + LayerNorm.
// ---------------------------------------------------------------------------
__global__ __launch_bounds__(256) void k4_update(const float* __restrict__ x,
                                                 const float* agg,
                                                 const unsigned short* __restrict__ w1t,
                                                 const float* __restrict__ b1,
                                                 const unsigned short* __restrict__ w2t,
                                                 const float* __restrict__ b2,
                                                 const float* __restrict__ lng,
                                                 const float* __restrict__ lnb,
                                                 const unsigned short* __restrict__ rest,
                                                 float* out) {
    __shared__ unsigned short A1[32 * 264];  // cat(x,agg) bf16, +8 pad
    __shared__ unsigned short A2[32 * 136];  // h1 bf16, +8 pad
    __shared__ float red_s[4][32];
    __shared__ float red_q[4][32];
    __shared__ float ln_mu[32];
    __shared__ float ln_rs[32];

    const int t = threadIdx.x;
    const int n0 = blockIdx.x * 32;
    const float4* x4 = (const float4*)x;
    const float4* agg4 = (const float4*)agg;

#pragma unroll
    for (int r = 0; r < 4; ++r) {
        const int idx = t + r * 256;
        const int node = idx >> 5, c4 = idx & 31;
        const float4 vx = x4[(n0 + node) * 32 + c4];
        const float4 va = agg4[(n0 + node) * 32 + c4];
        ushort4 px, pa;
        px.x = f2bf_(vx.x); px.y = f2bf_(vx.y); px.z = f2bf_(vx.z); px.w = f2bf_(vx.w);
        pa.x = f2bf_(va.x); pa.y = f2bf_(va.y); pa.z = f2bf_(va.z); pa.w = f2bf_(va.w);
        *(ushort4*)&A1[node * 264 + c4 * 4] = px;
        *(ushort4*)&A1[node * 264 + 128 + c4 * 4] = pa;
    }
    __syncthreads();

    const int w = t >> 6, lane = t & 63, nq = lane & 15, quad = lane >> 4;

    // ---- layer 1: [32x256] @ [256x128] ----
    f32x4 c1[2][2] = {};
#pragma unroll
    for (int ks = 0; ks < 8; ++ks) {
        const int k0 = ks * 32 + quad * 8;
        const short8 a0 = *(const short8*)&A1[(nq)*264 + k0];
        const short8 a1 = *(const short8*)&A1[(16 + nq) * 264 + k0];
        const short8 b0 = *(const short8*)&w1t[(w * 32 + nq) * 256 + k0];
        const short8 b1f = *(const short8*)&w1t[(w * 32 + 16 + nq) * 256 + k0];
        c1[0][0] = MFMA16(a0, b0, c1[0][0]);
        c1[0][1] = MFMA16(a0, b1f, c1[0][1]);
        c1[1][0] = MFMA16(a1, b0, c1[1][0]);
        c1[1][1] = MFMA16(a1, b1f, c1[1][1]);
    }
    const float b1c0 = b1[w * 32 + nq], b1c1 = b1[w * 32 + 16 + nq];
#pragma unroll
    for (int mt = 0; mt < 2; ++mt)
#pragma unroll
        for (int r = 0; r < 4; ++r) {
            const int row = mt * 16 + quad * 4 + r;
            A2[row * 136 + w * 32 + nq] = f2bf_(siluf_(c1[mt][0][r] + b1c0));
            A2[row * 136 + w * 32 + 16 + nq] = f2bf_(siluf_(c1[mt][1][r] + b1c1));
        }
    __syncthreads();

    // ---- layer 2 + residual ----
    f32x4 c2[2][2] = {};
#pragma unroll
    for (int ks = 0; ks < 4; ++ks) {
        const int k0 = ks * 32 + quad * 8;
        const short8 a0 = *(const short8*)&A2[(nq)*136 + k0];
        const short8 a1 = *(const short8*)&A2[(16 + nq) * 136 + k0];
        const short8 b0 = *(const short8*)&w2t[(w * 32 + nq) * 128 + k0];
        const short8 b1f = *(const short8*)&w2t[(w * 32 + 16 + nq) * 128 + k0];
        c2[0][0] = MFMA16(a0, b0, c2[0][0]);
        c2[0][1] = MFMA16(a0, b1f, c2[0][1]);
        c2[1][0] = MFMA16(a1, b0, c2[1][0]);
        c2[1][1] = MFMA16(a1, b1f, c2[1][1]);
    }
#pragma unroll
    for (int ks = 0; ks < 4; ++ks) {
        const int k0 = ks * 32 + quad * 8;
        const short8 a0 = *(const short8*)&A1[(nq)*264 + k0];       // x half
        const short8 a1 = *(const short8*)&A1[(16 + nq) * 264 + k0];
        const short8 b0 = *(const short8*)&rest[(w * 32 + nq) * 128 + k0];
        const short8 b1f = *(const short8*)&rest[(w * 32 + 16 + nq) * 128 + k0];
        c2[0][0] = MFMA16(a0, b0, c2[0][0]);
        c2[0][1] = MFMA16(a0, b1f, c2[0][1]);
        c2[1][0] = MFMA16(a1, b0, c2[1][0]);
        c2[1][1] = MFMA16(a1, b1f, c2[1][1]);
    }

    // ---- LayerNorm ----
    const float b2c0 = b2[w * 32 + nq], b2c1 = b2[w * 32 + 16 + nq];
    float vals[2][2][4];
#pragma unroll
    for (int mt = 0; mt < 2; ++mt)
#pragma unroll
        for (int r = 0; r < 4; ++r) {
            vals[mt][0][r] = c2[mt][0][r] + b2c0;
            vals[mt][1][r] = c2[mt][1][r] + b2c1;
        }
#pragma unroll
    for (int mt = 0; mt < 2; ++mt)
#pragma unroll
        for (int r = 0; r < 4; ++r) {
            float s = vals[mt][0][r] + vals[mt][1][r];
            float q = vals[mt][0][r] * vals[mt][0][r] + vals[mt][1][r] * vals[mt][1][r];
#pragma unroll
            for (int off = 1; off <= 8; off <<= 1) {
                s += __shfl_xor(s, off, 64);
                q += __shfl_xor(q, off, 64);
            }
            if (nq == 0) {
                const int row = mt * 16 + quad * 4 + r;
                red_s[w][row] = s;
                red_q[w][row] = q;
            }
        }
    __syncthreads();
    if (t < 32) {
        const float ts = red_s[0][t] + red_s[1][t] + red_s[2][t] + red_s[3][t];
        const float tq = red_q[0][t] + red_q[1][t] + red_q[2][t] + red_q[3][t];
        const float mu = ts * (1.0f / 128.0f);
        const float var = fmaxf(tq * (1.0f / 128.0f) - mu * mu, 0.f);
        ln_mu[t] = mu;
        ln_rs[t] = rsqrtf(var + LN_EPS);
    }
    __syncthreads();

    const float g0 = lng[w * 32 + nq], g1 = lng[w * 32 + 16 + nq];
    const float lb0 = lnb[w * 32 + nq], lb1 = lnb[w * 32 + 16 + nq];
#pragma unroll
    for (int mt = 0; mt < 2; ++mt)
#pragma unroll
        for (int r = 0; r < 4; ++r) {
            const int row = mt * 16 + quad * 4 + r;
            const float mu = ln_mu[row], rs = ln_rs[row];
            out[(n0 + row) * 128 + w * 32 + nq] = (vals[mt][0][r] - mu) * rs * g0 + lb0;
            out[(n0 + row) * 128 + w * 32 + 16 + nq] = (vals[mt][1][r] - mu) * rs * g1 + lb1;
        }
}

// ---------------------------------------------------------------------------
extern "C" void kernel_launch(void* const* d_in, const int* in_sizes, int n_in,
                              void* d_out, int out_size, void* d_ws, size_t ws_size,
                              hipStream_t stream) {
    const float* x = (const float*)d_in[0];
    const int* ei = (const int*)d_in[1];
    const float* eattr = (const float*)d_in[2];
    const float* aggW = (const float*)d_in[3];
    const float* aggb = (const float*)d_in[4];
    const float* eW1 = (const float*)d_in[5];
    const float* eb1 = (const float*)d_in[6];
    const float* eW2 = (const float*)d_in[7];
    const float* eb2 = (const float*)d_in[8];
    const float* uW1 = (const float*)d_in[9];
    const float* ub1 = (const float*)d_in[10];
    const float* uW2 = (const float*)d_in[11];
    const float* ub2 = (const float*)d_in[12];
    const float* lng = (const float*)d_in[13];
    const float* lnb = (const float*)d_in[14];
    const float* resW = (const float*)d_in[15];
    float* out = (float*)d_out;

    // workspace layout (bytes) — total ~48.2 MB (< out bytes = 51.2 MB)
    char* ws = (char*)d_ws;
    unsigned short* y16 = (unsigned short*)(ws + 0);          // 25.6 MB
    uint2* brec = (uint2*)(ws + 25600000);                    // 22.4 MB (6250*448*8)
    int* bcursor = (int*)(ws + 48000000);                     // 25,000 B
    unsigned short* w1t = (unsigned short*)(ws + 48025008);   // 65,536 B (16-aligned)
    unsigned short* w2t = (unsigned short*)(ws + 48090544);   // 32,768 B
    unsigned short* rest = (unsigned short*)(ws + 48123312);  // 32,768 B
    unsigned short* aggt = (unsigned short*)(ws + 48156080);  // 32,768 B -> 48,188,848
    float* agg = out;  // aliased onto d_out (safe: block-local rows in K4)

    const int* src = ei;
    const int* dst = ei + N_EDGES;

    kw<<<346, 256, 0, stream>>>(uW1, uW2, resW, aggW, w1t, w2t, rest, aggt, bcursor);
    k1_y<<<N_NODES / 32, 256, 0, stream>>>(x, aggt, aggb, y16);
    p3g<<<N_EDGES / 256, 128, 0, stream>>>(eattr, eW1, eb1, eW2, eb2,
                                           src, dst, bcursor, brec);
    pB<<<N_BUCKETS, 256, 0, stream>>>(y16, bcursor, brec, agg);
    k4_update<<<N_NODES / 32, 256, 0, stream>>>(x, agg, w1t, ub1, w2t, ub2, lng, lnb, rest, out);
}

// Round 11
// 358.508 us; speedup vs baseline: 3.7540x; 3.7540x over previous
//
#include <hip/hip_runtime.h>
#include <math.h>

#define N_NODES 100000
#define N_EDGES 1600000
#define LN_EPS 1e-5f

// bucketed aggregation: 16 nodes per bucket, FIXED-capacity segments
#define B_SHIFT 4
#define B_NODES 16
#define N_BUCKETS 6250           // 100000 / 16
#define SEG_CAP 448              // fixed slots/bucket (mean 256, max~330 @12 sigma)

typedef __attribute__((ext_vector_type(8))) short short8;
typedef __attribute__((ext_vector_type(4))) float f32x4;
#define MFMA16(a, b, c) __builtin_amdgcn_mfma_f32_16x16x32_bf16(a, b, c, 0, 0, 0)

#define LOG2E 1.442695040888963f

#if __has_builtin(__builtin_amdgcn_exp2f) && __has_builtin(__builtin_amdgcn_rcpf)
__device__ __forceinline__ float sigmoidf_(float v) {
    return __builtin_amdgcn_rcpf(1.0f + __builtin_amdgcn_exp2f(-LOG2E * v));
}
#else
__device__ __forceinline__ float sigmoidf_(float v) { return 1.0f / (1.0f + __expf(-v)); }
#endif
__device__ __forceinline__ float siluf_(float v) { return v * sigmoidf_(v); }

// bf16 pack (round-to-nearest-even)
__device__ __forceinline__ unsigned short f2bf_(float f) {
    unsigned int u = __float_as_uint(f);
    unsigned int rounded = u + 0x7FFF + ((u >> 16) & 1);
    return (unsigned short)(rounded >> 16);
}

// ---------------------------------------------------------------------------
// KW: convert + transpose weights to bf16 [n][k]; ALSO inits bucket cursors
// (folded p3i: one fewer dispatch).
// ---------------------------------------------------------------------------
__global__ __launch_bounds__(256) void kw(const float* __restrict__ W1,
                                          const float* __restrict__ W2,
                                          const float* __restrict__ resW,
                                          const float* __restrict__ aggW,
                                          unsigned short* __restrict__ w1t,
                                          unsigned short* __restrict__ w2t,
                                          unsigned short* __restrict__ rest,
                                          unsigned short* __restrict__ aggt,
                                          int* __restrict__ bcursor) {
    const int idx = blockIdx.x * 256 + threadIdx.x;  // 0..88575
    if (idx < 32768) {
        const int n = idx >> 8, k = idx & 255;
        w1t[idx] = f2bf_(W1[k * 128 + n]);
    } else if (idx < 49152) {
        const int i = idx - 32768, n = i >> 7, k = i & 127;
        w2t[i] = f2bf_(W2[k * 128 + n]);
    } else if (idx < 65536) {
        const int i = idx - 49152, n = i >> 7, k = i & 127;
        rest[i] = f2bf_(resW[k * 128 + n]);
    } else if (idx < 81920) {
        const int i = idx - 65536, n = i >> 7, k = i & 127;
        aggt[i] = f2bf_(aggW[k * 128 + n]);
    } else if (idx < 81920 + N_BUCKETS) {
        const int n = idx - 81920;
        bcursor[n] = n * SEG_CAP;
    }
}

// ---------------------------------------------------------------------------
// K1 (MFMA): y16 = bf16( silu(x @ aggW + b) ).  32 nodes/block, 256 thr.
// ---------------------------------------------------------------------------
__global__ __launch_bounds__(256) void k1_y(const float* __restrict__ x,
                                            const unsigned short* __restrict__ aggt,
                                            const float* __restrict__ b,
                                            unsigned short* __restrict__ y16) {
    __shared__ unsigned short A1[32 * 136];
    __shared__ unsigned short O[32 * 136];
    const int t = threadIdx.x;
    const int n0 = blockIdx.x * 32;
    const float4* x4 = (const float4*)x;

#pragma unroll
    for (int r = 0; r < 4; ++r) {
        const int idx = t + r * 256;          // 32 nodes x 32 float4
        const int node = idx >> 5, c4 = idx & 31;
        const float4 v = x4[(n0 + node) * 32 + c4];
        ushort4 p;
        p.x = f2bf_(v.x); p.y = f2bf_(v.y); p.z = f2bf_(v.z); p.w = f2bf_(v.w);
        *(ushort4*)&A1[node * 136 + c4 * 4] = p;
    }
    __syncthreads();

    const int w = t >> 6, lane = t & 63, nq = lane & 15, quad = lane >> 4;
    f32x4 c[2][2] = {};
#pragma unroll
    for (int ks = 0; ks < 4; ++ks) {
        const int k0 = ks * 32 + quad * 8;
        const short8 a0 = *(const short8*)&A1[(nq)*136 + k0];
        const short8 a1 = *(const short8*)&A1[(16 + nq) * 136 + k0];
        const short8 b0 = *(const short8*)&aggt[(w * 32 + nq) * 128 + k0];
        const short8 b1 = *(const short8*)&aggt[(w * 32 + 16 + nq) * 128 + k0];
        c[0][0] = MFMA16(a0, b0, c[0][0]);
        c[0][1] = MFMA16(a0, b1, c[0][1]);
        c[1][0] = MFMA16(a1, b0, c[1][0]);
        c[1][1] = MFMA16(a1, b1, c[1][1]);
    }
    const float bc0 = b[w * 32 + nq], bc1 = b[w * 32 + 16 + nq];
#pragma unroll
    for (int mt = 0; mt < 2; ++mt)
#pragma unroll
        for (int r = 0; r < 4; ++r) {
            const int row = mt * 16 + quad * 4 + r;
            O[row * 136 + w * 32 + nq] = f2bf_(siluf_(c[mt][0][r] + bc0));
            O[row * 136 + w * 32 + 16 + nq] = f2bf_(siluf_(c[mt][1][r] + bc1));
        }
    __syncthreads();

#pragma unroll
    for (int r = 0; r < 2; ++r) {
        const int idx = t + r * 256;          // 32 rows x 16 chunks(16B)
        const int row = idx >> 4, c8 = idx & 15;
        const short8 v = *(const short8*)&O[row * 136 + c8 * 8];
        *(short8*)&y16[(n0 + row) * 128 + c8 * 8] = v;
    }
}

// ---------------------------------------------------------------------------
// P3G (fused gate + scatter), 2 edges/thread, 128-thread blocks, 6250 blocks.
// Plateaued at ~101us across 6 configs (r4-r9); left at the verified-best.
// ---------------------------------------------------------------------------
__global__ __launch_bounds__(128) void p3g(const float* __restrict__ attr,
                                           const float* __restrict__ W1,
                                           const float* __restrict__ b1,
                                           const float* __restrict__ W2,
                                           const float* __restrict__ b2,
                                           const int* __restrict__ src,
                                           const int* __restrict__ dst,
                                           int* __restrict__ bcursor,
                                           uint2* __restrict__ brec) {
    __shared__ float4 W1s[128];
    __shared__ float4 W2s[32];
    __shared__ float4 b1s[32];
    const int t = threadIdx.x;
    W1s[t] = ((const float4*)W1)[t];          // 128 threads cover W1 exactly
    if (t < 32) {
        W2s[t] = ((const float4*)W2)[t];
        b1s[t] = ((const float4*)b1)[t];
    }
    __syncthreads();

    const int e0 = blockIdx.x * 256 + t;      // 6250 blocks x 256 edges
    const int e1 = e0 + 128;
    const float4 a0 = ((const float4*)attr)[e0];
    const float4 a1 = ((const float4*)attr)[e1];
    const int s0 = src[e0], s1 = src[e1];
    const int d0 = dst[e0], d1 = dst[e1];
    float acc0 = 0.f, acc1 = 0.f;
#pragma unroll 8
    for (int j4 = 0; j4 < 32; ++j4) {
        const float4 r0 = W1s[j4];
        const float4 r1 = W1s[32 + j4];
        const float4 r2 = W1s[64 + j4];
        const float4 r3 = W1s[96 + j4];
        const float4 bb = b1s[j4];
        const float4 w2v = W2s[j4];
        // edge 0
        float hx = fmaf(a0.x, r0.x, fmaf(a0.y, r1.x, fmaf(a0.z, r2.x, fmaf(a0.w, r3.x, bb.x))));
        float hy = fmaf(a0.x, r0.y, fmaf(a0.y, r1.y, fmaf(a0.z, r2.y, fmaf(a0.w, r3.y, bb.y))));
        float hz = fmaf(a0.x, r0.z, fmaf(a0.y, r1.z, fmaf(a0.z, r2.z, fmaf(a0.w, r3.z, bb.z))));
        float hw = fmaf(a0.x, r0.w, fmaf(a0.y, r1.w, fmaf(a0.z, r2.w, fmaf(a0.w, r3.w, bb.w))));
        // edge 1 (independent chain — fills trans/fma latency of edge 0)
        float gx = fmaf(a1.x, r0.x, fmaf(a1.y, r1.x, fmaf(a1.z, r2.x, fmaf(a1.w, r3.x, bb.x))));
        float gy = fmaf(a1.x, r0.y, fmaf(a1.y, r1.y, fmaf(a1.z, r2.y, fmaf(a1.w, r3.y, bb.y))));
        float gz = fmaf(a1.x, r0.z, fmaf(a1.y, r1.z, fmaf(a1.z, r2.z, fmaf(a1.w, r3.z, bb.z))));
        float gw = fmaf(a1.x, r0.w, fmaf(a1.y, r1.w, fmaf(a1.z, r2.w, fmaf(a1.w, r3.w, bb.w))));
        acc0 = fmaf(siluf_(hx), w2v.x, acc0);
        acc1 = fmaf(siluf_(gx), w2v.x, acc1);
        acc0 = fmaf(siluf_(hy), w2v.y, acc0);
        acc1 = fmaf(siluf_(gy), w2v.y, acc1);
        acc0 = fmaf(siluf_(hz), w2v.z, acc0);
        acc1 = fmaf(siluf_(gz), w2v.z, acc1);
        acc0 = fmaf(siluf_(hw), w2v.w, acc0);
        acc1 = fmaf(siluf_(gw), w2v.w, acc1);
    }
    const float b2c = b2[0];
    const float ew0 = sigmoidf_(acc0 + b2c);
    const float ew1 = sigmoidf_(acc1 + b2c);
    const int bk0 = d0 >> B_SHIFT;
    const int slot0 = atomicAdd(&bcursor[bk0], 1);
    if (slot0 < (bk0 + 1) * SEG_CAP)   // capacity guard (unreachable for this input)
        brec[slot0] = make_uint2((unsigned)s0 | ((unsigned)(d0 & (B_NODES - 1)) << 27),
                                 __float_as_uint(ew0));
    const int bk1 = d1 >> B_SHIFT;
    const int slot1 = atomicAdd(&bcursor[bk1], 1);
    if (slot1 < (bk1 + 1) * SEG_CAP)
        brec[slot1] = make_uint2((unsigned)s1 | ((unsigned)(d1 & (B_NODES - 1)) << 27),
                                 __float_as_uint(ew1));
}

// ---------------------------------------------------------------------------
// PB: one block per bucket, 512 threads (8 waves). LDS counting-sort by
// dstLocal, then per-node gather-accumulate in REGISTERS (r10 lesson: LDS
// atomics are ~20x worse). 8 waves double in-flight gathers vs 4 (pB is
// latency-bound: r10 counters show HBM 2.8%). Each wave owns 2 nodes.
// ---------------------------------------------------------------------------
__global__ __launch_bounds__(512) void pB(const unsigned short* __restrict__ y16,
                                          const int* __restrict__ bcursor,
                                          const uint2* __restrict__ brec,
                                          float* __restrict__ agg) {
    __shared__ uint2 raw[SEG_CAP];     // 3.5 KB
    __shared__ uint2 srec[SEG_CAP];    // 3.5 KB
    __shared__ int hist[B_NODES];
    __shared__ int nstart[B_NODES];
    __shared__ int ncur[B_NODES];

    const int t = threadIdx.x;
    const int b = blockIdx.x;
    const int base = b * SEG_CAP;
    int c = bcursor[b] - base;
    if (c > SEG_CAP) c = SEG_CAP;  // guards LDS (unreachable for this input)

    if (t < B_NODES) hist[t] = 0;
    __syncthreads();

    for (int i = t; i < c; i += 512) {
        const uint2 r = brec[base + i];
        raw[i] = r;
        atomicAdd(&hist[r.x >> 27], 1);
    }
    __syncthreads();

    if (t == 0) {
        int acc = 0;
#pragma unroll
        for (int d = 0; d < B_NODES; ++d) {
            nstart[d] = acc;
            ncur[d] = acc;
            acc += hist[d];
        }
    }
    __syncthreads();

    for (int i = t; i < c; i += 512) {
        const uint2 r = raw[i];
        const int slot = atomicAdd(&ncur[r.x >> 27], 1);
        srec[slot] = r;
    }
    __syncthreads();

    const int w = t >> 6, lane = t & 63;   // w in 0..7
    const unsigned int* y32 = (const unsigned int*)y16;
#pragma unroll
    for (int rep = 0; rep < 2; ++rep) {
        const int d = w + rep * 8;
        const int st = nstart[d];
        const int cd = hist[d];
        const int end = st + cd;
        float ax0 = 0.f, ay0 = 0.f, ax1 = 0.f, ay1 = 0.f;
        float ax2 = 0.f, ay2 = 0.f, ax3 = 0.f, ay3 = 0.f;
        int p = st;
        for (; p + 8 <= end; p += 8) {
            const uint2 r0 = srec[p];
            const uint2 r1 = srec[p + 1];
            const uint2 r2 = srec[p + 2];
            const uint2 r3 = srec[p + 3];
            const uint2 r4 = srec[p + 4];
            const uint2 r5 = srec[p + 5];
            const uint2 r6 = srec[p + 6];
            const uint2 r7 = srec[p + 7];
            const unsigned int u0 = y32[(r0.x & 0x7FFFFFFu) * 64 + lane];
            const unsigned int u1 = y32[(r1.x & 0x7FFFFFFu) * 64 + lane];
            const unsigned int u2 = y32[(r2.x & 0x7FFFFFFu) * 64 + lane];
            const unsigned int u3 = y32[(r3.x & 0x7FFFFFFu) * 64 + lane];
            const unsigned int u4 = y32[(r4.x & 0x7FFFFFFu) * 64 + lane];
            const unsigned int u5 = y32[(r5.x & 0x7FFFFFFu) * 64 + lane];
            const unsigned int u6 = y32[(r6.x & 0x7FFFFFFu) * 64 + lane];
            const unsigned int u7 = y32[(r7.x & 0x7FFFFFFu) * 64 + lane];
            const float w0 = __uint_as_float(r0.y);
            const float w1 = __uint_as_float(r1.y);
            const float w2 = __uint_as_float(r2.y);
            const float w3 = __uint_as_float(r3.y);
            const float w4 = __uint_as_float(r4.y);
            const float w5 = __uint_as_float(r5.y);
            const float w6 = __uint_as_float(r6.y);
            const float w7 = __uint_as_float(r7.y);
            ax0 = fmaf(__uint_as_float(u0 << 16), w0, ax0);
            ay0 = fmaf(__uint_as_float(u0 & 0xFFFF0000u), w0, ay0);
            ax1 = fmaf(__uint_as_float(u1 << 16), w1, ax1);
            ay1 = fmaf(__uint_as_float(u1 & 0xFFFF0000u), w1, ay1);
            ax2 = fmaf(__uint_as_float(u2 << 16), w2, ax2);
            ay2 = fmaf(__uint_as_float(u2 & 0xFFFF0000u), w2, ay2);
            ax3 = fmaf(__uint_as_float(u3 << 16), w3, ax3);
            ay3 = fmaf(__uint_as_float(u3 & 0xFFFF0000u), w3, ay3);
            ax0 = fmaf(__uint_as_float(u4 << 16), w4, ax0);
            ay0 = fmaf(__uint_as_float(u4 & 0xFFFF0000u), w4, ay0);
            ax1 = fmaf(__uint_as_float(u5 << 16), w5, ax1);
            ay1 = fmaf(__uint_as_float(u5 & 0xFFFF0000u), w5, ay1);
            ax2 = fmaf(__uint_as_float(u6 << 16), w6, ax2);
            ay2 = fmaf(__uint_as_float(u6 & 0xFFFF0000u), w6, ay2);
            ax3 = fmaf(__uint_as_float(u7 << 16), w7, ax3);
            ay3 = fmaf(__uint_as_float(u7 & 0xFFFF0000u), w7, ay3);
        }
        for (; p + 4 <= end; p += 4) {
            const uint2 r0 = srec[p];
            const uint2 r1 = srec[p + 1];
            const uint2 r2 = srec[p + 2];
            const uint2 r3 = srec[p + 3];
            const unsigned int u0 = y32[(r0.x & 0x7FFFFFFu) * 64 + lane];
            const unsigned int u1 = y32[(r1.x & 0x7FFFFFFu) * 64 + lane];
            const unsigned int u2 = y32[(r2.x & 0x7FFFFFFu) * 64 + lane];
            const unsigned int u3 = y32[(r3.x & 0x7FFFFFFu) * 64 + lane];
            const float w0 = __uint_as_float(r0.y);
            const float w1 = __uint_as_float(r1.y);
            const float w2 = __uint_as_float(r2.y);
            const float w3 = __uint_as_float(r3.y);
            ax0 = fmaf(__uint_as_float(u0 << 16), w0, ax0);
            ay0 = fmaf(__uint_as_float(u0 & 0xFFFF0000u), w0, ay0);
            ax1 = fmaf(__uint_as_float(u1 << 16), w1, ax1);
            ay1 = fmaf(__uint_as_float(u1 & 0xFFFF0000u), w1, ay1);
            ax2 = fmaf(__uint_as_float(u2 << 16), w2, ax2);
            ay2 = fmaf(__uint_as_float(u2 & 0xFFFF0000u), w2, ay2);
            ax3 = fmaf(__uint_as_float(u3 << 16), w3, ax3);
            ay3 = fmaf(__uint_as_float(u3 & 0xFFFF0000u), w3, ay3);
        }
        for (; p < end; ++p) {
            const uint2 r0 = srec[p];
            const unsigned int u0 = y32[(r0.x & 0x7FFFFFFu) * 64 + lane];
            const float w0 = __uint_as_float(r0.y);
            ax0 = fmaf(__uint_as_float(u0 << 16), w0, ax0);
            ay0 = fmaf(__uint_as_float(u0 & 0xFFFF0000u), w0, ay0);
        }
        const float accx = (ax0 + ax1) + (ax2 + ax3);
        const float accy = (ay0 + ay1) + (ay2 + ay3);
        const float inv = 1.0f / fmaxf((float)cd, 1.0f);
        const int n = b * B_NODES + d;
        ((float2*)agg)[n * 64 + lane] = make_float2(accx * inv, accy * inv);
    }
}

// ---------------------------------------------------------------------------
// K4 (MFMA): fused update MLP + residual + LayerNorm.
// ---------------------------------------------------------------------------
__global__ __launch_bounds__(256) void k4_update(const float* __restrict__ x,
                                                 const float* agg,
                                                 const unsigned short* __restrict__ w1t,
                                                 const float* __restrict__ b1,
                                                 const unsigned short* __restrict__ w2t,
                                                 const float* __restrict__ b2,
                                                 const float* __restrict__ lng,
                                                 const float* __restrict__ lnb,
                                                 const unsigned short* __restrict__ rest,
                                                 float* out) {
    __shared__ unsigned short A1[32 * 264];  // cat(x,agg) bf16, +8 pad
    __shared__ unsigned short A2[32 * 136];  // h1 bf16, +8 pad
    __shared__ float red_s[4][32];
    __shared__ float red_q[4][32];
    __shared__ float ln_mu[32];
    __shared__ float ln_rs[32];

    const int t = threadIdx.x;
    const int n0 = blockIdx.x * 32;
    const float4* x4 = (const float4*)x;
    const float4* agg4 = (const float4*)agg;

#pragma unroll
    for (int r = 0; r < 4; ++r) {
        const int idx = t + r * 256;
        const int node = idx >> 5, c4 = idx & 31;
        const float4 vx = x4[(n0 + node) * 32 + c4];
        const float4 va = agg4[(n0 + node) * 32 + c4];
        ushort4 px, pa;
        px.x = f2bf_(vx.x); px.y = f2bf_(vx.y); px.z = f2bf_(vx.z); px.w = f2bf_(vx.w);
        pa.x = f2bf_(va.x); pa.y = f2bf_(va.y); pa.z = f2bf_(va.z); pa.w = f2bf_(va.w);
        *(ushort4*)&A1[node * 264 + c4 * 4] = px;
        *(ushort4*)&A1[node * 264 + 128 + c4 * 4] = pa;
    }
    __syncthreads();

    const int w = t >> 6, lane = t & 63, nq = lane & 15, quad = lane >> 4;

    // ---- layer 1: [32x256] @ [256x128] ----
    f32x4 c1[2][2] = {};
#pragma unroll
    for (int ks = 0; ks < 8; ++ks) {
        const int k0 = ks * 32 + quad * 8;
        const short8 a0 = *(const short8*)&A1[(nq)*264 + k0];
        const short8 a1 = *(const short8*)&A1[(16 + nq) * 264 + k0];
        const short8 b0 = *(const short8*)&w1t[(w * 32 + nq) * 256 + k0];
        const short8 b1f = *(const short8*)&w1t[(w * 32 + 16 + nq) * 256 + k0];
        c1[0][0] = MFMA16(a0, b0, c1[0][0]);
        c1[0][1] = MFMA16(a0, b1f, c1[0][1]);
        c1[1][0] = MFMA16(a1, b0, c1[1][0]);
        c1[1][1] = MFMA16(a1, b1f, c1[1][1]);
    }
    const float b1c0 = b1[w * 32 + nq], b1c1 = b1[w * 32 + 16 + nq];
#pragma unroll
    for (int mt = 0; mt < 2; ++mt)
#pragma unroll
        for (int r = 0; r < 4; ++r) {
            const int row = mt * 16 + quad * 4 + r;
            A2[row * 136 + w * 32 + nq] = f2bf_(siluf_(c1[mt][0][r] + b1c0));
            A2[row * 136 + w * 32 + 16 + nq] = f2bf_(siluf_(c1[mt][1][r] + b1c1));
        }
    __syncthreads();

    // ---- layer 2 + residual ----
    f32x4 c2[2][2] = {};
#pragma unroll
    for (int ks = 0; ks < 4; ++ks) {
        const int k0 = ks * 32 + quad * 8;
        const short8 a0 = *(const short8*)&A2[(nq)*136 + k0];
        const short8 a1 = *(const short8*)&A2[(16 + nq) * 136 + k0];
        const short8 b0 = *(const short8*)&w2t[(w * 32 + nq) * 128 + k0];
        const short8 b1f = *(const short8*)&w2t[(w * 32 + 16 + nq) * 128 + k0];
        c2[0][0] = MFMA16(a0, b0, c2[0][0]);
        c2[0][1] = MFMA16(a0, b1f, c2[0][1]);
        c2[1][0] = MFMA16(a1, b0, c2[1][0]);
        c2[1][1] = MFMA16(a1, b1f, c2[1][1]);
    }
#pragma unroll
    for (int ks = 0; ks < 4; ++ks) {
        const int k0 = ks * 32 + quad * 8;
        const short8 a0 = *(const short8*)&A1[(nq)*264 + k0];       // x half
        const short8 a1 = *(const short8*)&A1[(16 + nq) * 264 + k0];
        const short8 b0 = *(const short8*)&rest[(w * 32 + nq) * 128 + k0];
        const short8 b1f = *(const short8*)&rest[(w * 32 + 16 + nq) * 128 + k0];
        c2[0][0] = MFMA16(a0, b0, c2[0][0]);
        c2[0][1] = MFMA16(a0, b1f, c2[0][1]);
        c2[1][0] = MFMA16(a1, b0, c2[1][0]);
        c2[1][1] = MFMA16(a1, b1f, c2[1][1]);
    }

    // ---- LayerNorm ----
    const float b2c0 = b2[w * 32 + nq], b2c1 = b2[w * 32 + 16 + nq];
    float vals[2][2][4];
#pragma unroll
    for (int mt = 0; mt < 2; ++mt)
#pragma unroll
        for (int r = 0; r < 4; ++r) {
            vals[mt][0][r] = c2[mt][0][r] + b2c0;
            vals[mt][1][r] = c2[mt][1][r] + b2c1;
        }
#pragma unroll
    for (int mt = 0; mt < 2; ++mt)
#pragma unroll
        for (int r = 0; r < 4; ++r) {
            float s = vals[mt][0][r] + vals[mt][1][r];
            float q = vals[mt][0][r] * vals[mt][0][r] + vals[mt][1][r] * vals[mt][1][r];
#pragma unroll
            for (int off = 1; off <= 8; off <<= 1) {
                s += __shfl_xor(s, off, 64);
                q += __shfl_xor(q, off, 64);
            }
            if (nq == 0) {
                const int row = mt * 16 + quad * 4 + r;
                red_s[w][row] = s;
                red_q[w][row] = q;
            }
        }
    __syncthreads();
    if (t < 32) {
        const float ts = red_s[0][t] + red_s[1][t] + red_s[2][t] + red_s[3][t];
        const float tq = red_q[0][t] + red_q[1][t] + red_q[2][t] + red_q[3][t];
        const float mu = ts * (1.0f / 128.0f);
        const float var = fmaxf(tq * (1.0f / 128.0f) - mu * mu, 0.f);
        ln_mu[t] = mu;
        ln_rs[t] = rsqrtf(var + LN_EPS);
    }
    __syncthreads();

    const float g0 = lng[w * 32 + nq], g1 = lng[w * 32 + 16 + nq];
    const float lb0 = lnb[w * 32 + nq], lb1 = lnb[w * 32 + 16 + nq];
#pragma unroll
    for (int mt = 0; mt < 2; ++mt)
#pragma unroll
        for (int r = 0; r < 4; ++r) {
            const int row = mt * 16 + quad * 4 + r;
            const float mu = ln_mu[row], rs = ln_rs[row];
            out[(n0 + row) * 128 + w * 32 + nq] = (vals[mt][0][r] - mu) * rs * g0 + lb0;
            out[(n0 + row) * 128 + w * 32 + 16 + nq] = (vals[mt][1][r] - mu) * rs * g1 + lb1;
        }
}

// ---------------------------------------------------------------------------
extern "C" void kernel_launch(void* const* d_in, const int* in_sizes, int n_in,
                              void* d_out, int out_size, void* d_ws, size_t ws_size,
                              hipStream_t stream) {
    const float* x = (const float*)d_in[0];
    const int* ei = (const int*)d_in[1];
    const float* eattr = (const float*)d_in[2];
    const float* aggW = (const float*)d_in[3];
    const float* aggb = (const float*)d_in[4];
    const float* eW1 = (const float*)d_in[5];
    const float* eb1 = (const float*)d_in[6];
    const float* eW2 = (const float*)d_in[7];
    const float* eb2 = (const float*)d_in[8];
    const float* uW1 = (const float*)d_in[9];
    const float* ub1 = (const float*)d_in[10];
    const float* uW2 = (const float*)d_in[11];
    const float* ub2 = (const float*)d_in[12];
    const float* lng = (const float*)d_in[13];
    const float* lnb = (const float*)d_in[14];
    const float* resW = (const float*)d_in[15];
    float* out = (float*)d_out;

    // workspace layout (bytes) — total ~48.2 MB (< out bytes = 51.2 MB)
    char* ws = (char*)d_ws;
    unsigned short* y16 = (unsigned short*)(ws + 0);          // 25.6 MB
    uint2* brec = (uint2*)(ws + 25600000);                    // 22.4 MB (6250*448*8)
    int* bcursor = (int*)(ws + 48000000);                     // 25,000 B
    unsigned short* w1t = (unsigned short*)(ws + 48025008);   // 65,536 B (16-aligned)
    unsigned short* w2t = (unsigned short*)(ws + 48090544);   // 32,768 B
    unsigned short* rest = (unsigned short*)(ws + 48123312);  // 32,768 B
    unsigned short* aggt = (unsigned short*)(ws + 48156080);  // 32,768 B -> 48,188,848
    float* agg = out;  // aliased onto d_out (safe: block-local rows in K4)

    const int* src = ei;
    const int* dst = ei + N_EDGES;

    kw<<<346, 256, 0, stream>>>(uW1, uW2, resW, aggW, w1t, w2t, rest, aggt, bcursor);
    k1_y<<<N_NODES / 32, 256, 0, stream>>>(x, aggt, aggb, y16);
    p3g<<<N_EDGES / 256, 128, 0, stream>>>(eattr, eW1, eb1, eW2, eb2,
                                           src, dst, bcursor, brec);
    pB<<<N_BUCKETS, 512, 0, stream>>>(y16, bcursor, brec, agg);
    k4_update<<<N_NODES / 32, 256, 0, stream>>>(x, agg, w1t, ub1, w2t, ub2, lng, lnb, rest, out);
}